// Round 1
// baseline (184.484 us; speedup 1.0000x reference)
//
#include <hip/hip_runtime.h>
#include <stdint.h>

// OpenBoundary neighbour-list build, N=8192, cutoff=0.125, max_neighbours=128.
// Outputs (int32, concatenated in d_out):
//   to_idx       [N, M]      first M neighbour indices (ascending), pad -1
//   cell_indices [N, M, 3]   all zeros (open boundary)
//   actual_max_neighbours    scalar = max uncapped neighbour count
//
// Structure: one wave64 per row. Positions staged in LDS as padded float4
// tiles (ds_read_b128 per lane per candidate). Per-64-candidate chunk:
// distance test -> __ballot -> popcount prefix -> ordered compacted write.
// Ascending (tile, chunk, lane) iteration == jnp.argwhere row order.

#define CUTOFF2 (0.125f * 0.125f)
#define MASKV (-1)

constexpr int BLOCK = 1024;           // 16 waves -> 16 rows per block
constexpr int WAVES = BLOCK / 64;
constexpr int TILE  = 2048;           // positions per LDS tile (32 KB as float4)

__global__ __launch_bounds__(BLOCK) void openboundary_neigh_kernel(
    const float* __restrict__ pos,    // [n,3] float32
    int n, int maxn,
    int* __restrict__ to_idx,         // [n, maxn]
    int* __restrict__ out_max)        // scalar (pre-zeroed)
{
    __shared__ float4 sp[TILE];
    float* spf = (float*)sp;

    const int lane = threadIdx.x & 63;
    const int wave = threadIdx.x >> 6;
    const int r0   = blockIdx.x * WAVES + wave;
    const bool valid = (r0 < n);
    const int row  = valid ? r0 : 0;

    // centre position for this wave's row (wave-uniform; scalar-cached)
    const float cx = pos[(size_t)row * 3 + 0];
    const float cy = pos[(size_t)row * 3 + 1];
    const float cz = pos[(size_t)row * 3 + 2];

    int* __restrict__ out_row = to_idx + (size_t)row * maxn;
    int base = 0;   // running neighbour count (uncapped), wave-uniform

    for (int t = 0; t < n; t += TILE) {
        const int lim = (n - t) < TILE ? (n - t) : TILE;   // positions this tile

        // cooperative coalesced load: lim*3 floats -> padded float4 LDS
        for (int e = threadIdx.x; e < lim * 3; e += BLOCK) {
            int p = e / 3;
            int comp = e - p * 3;
            spf[p * 4 + comp] = pos[(size_t)t * 3 + e];
        }
        __syncthreads();

        const int nchunks = lim >> 6;   // n is a multiple of 64
        for (int c = 0; c < nchunks; ++c) {
            const int j = t + c * 64 + lane;
            const float4 q = sp[c * 64 + lane];          // ds_read_b128
            const float dx = q.x - cx;
            const float dy = q.y - cy;
            const float dz = q.z - cz;
            const float d2 = dx * dx + dy * dy + dz * dz;
            const bool pred = (d2 <= CUTOFF2) && (j != row);

            const unsigned long long m = __ballot(pred);
            const int before = __popcll(m & ((1ull << lane) - 1ull));
            const int p = base + before;
            if (pred && valid && p < maxn) out_row[p] = j;
            base += __popcll(m);
        }
        __syncthreads();
    }

    if (valid) {
        // pad remainder with -1 (capped start)
        const int start = base < maxn ? base : maxn;
        for (int p = start + lane; p < maxn; p += 64) out_row[p] = MASKV;
        if (lane == 0) atomicMax(out_max, base);
    }
}

extern "C" void kernel_launch(void* const* d_in, const int* in_sizes, int n_in,
                              void* d_out, int out_size, void* d_ws, size_t ws_size,
                              hipStream_t stream) {
    const float* pos = (const float*)d_in[0];
    const int n = in_sizes[0] / 3;                       // 8192
    const int maxn = (out_size - 1) / (n * 4);           // 128

    int* to_idx  = (int*)d_out;
    int* cells   = to_idx + (size_t)n * maxn;            // [n, maxn, 3]
    int* out_max = cells + (size_t)n * maxn * 3;         // scalar

    // zero cell_indices + the scalar in one memset (graph-capture safe)
    hipMemsetAsync(cells, 0, ((size_t)n * maxn * 3 + 1) * sizeof(int), stream);

    const int grid = (n + WAVES - 1) / WAVES;            // 512 blocks
    openboundary_neigh_kernel<<<grid, BLOCK, 0, stream>>>(pos, n, maxn, to_idx, out_max);
}

// Round 2
// 174.746 us; speedup vs baseline: 1.0557x; 1.0557x over previous
//
#include <hip/hip_runtime.h>
#include <stdint.h>

// OpenBoundary neighbour list via spatial binning.
// Grid 8x8x8, cell edge 0.125 == cutoff, so neighbours live in the 27-cell
// stencil. Pipeline (all on `stream`, graph-capture safe):
//   1. count_kernel   : per-cell population (atomics into zeroed ws)
//   2. scan_kernel    : exclusive scan of 512 counts -> offsets[513]
//   3. scatter_kernel : cell-sorted float4 array, original index in .w bits
//   4. neigh_kernel   : one wave64 per row; 9 contiguous segments (x-runs of
//      the 3x3x3 stencil), ballot-compacted hits into per-wave LDS, then a
//      128-slot bitonic sort to restore ascending original-index order
//      (jnp.argwhere semantics), write 128 slots padded with -1.
// cell_indices [N,128,3] and the scalar slot are zeroed by one memset; the
// scalar then gets atomicMax of the uncapped per-row count.

#define CUTOFF2 (0.125f * 0.125f)
constexpr int NCELLS = 512;   // 8^3
constexpr int MAXHIT = 128;   // sort capacity == max_neighbours

__device__ __forceinline__ int cell_of(float x, float y, float z) {
    int cx = (int)(x * 8.0f); cx = cx > 7 ? 7 : cx;
    int cy = (int)(y * 8.0f); cy = cy > 7 ? 7 : cy;
    int cz = (int)(z * 8.0f); cz = cz > 7 ? 7 : cz;
    return (cz * 8 + cy) * 8 + cx;
}

__global__ void count_kernel(const float* __restrict__ pos, int n,
                             int* __restrict__ cnt) {
    int i = blockIdx.x * blockDim.x + threadIdx.x;
    if (i >= n) return;
    atomicAdd(&cnt[cell_of(pos[i*3], pos[i*3+1], pos[i*3+2])], 1);
}

__global__ __launch_bounds__(NCELLS) void scan_kernel(const int* __restrict__ cnt,
                                                      int* __restrict__ offs) {
    __shared__ int s[NCELLS];
    int t = threadIdx.x;
    s[t] = cnt[t];
    __syncthreads();
    for (int d = 1; d < NCELLS; d <<= 1) {
        int v = (t >= d) ? s[t - d] : 0;
        __syncthreads();
        s[t] += v;
        __syncthreads();
    }
    offs[t + 1] = s[t];          // inclusive -> exclusive shifted
    if (t == 0) offs[0] = 0;
}

__global__ void scatter_kernel(const float* __restrict__ pos, int n,
                               const int* __restrict__ offs,
                               int* __restrict__ cursor,
                               float4* __restrict__ sorted) {
    int i = blockIdx.x * blockDim.x + threadIdx.x;
    if (i >= n) return;
    float x = pos[i*3], y = pos[i*3+1], z = pos[i*3+2];
    int c = cell_of(x, y, z);
    int slot = offs[c] + atomicAdd(&cursor[c], 1);
    sorted[slot] = make_float4(x, y, z, __int_as_float(i));
}

__global__ __launch_bounds__(64) void neigh_kernel(
    const float4* __restrict__ sorted,
    const int* __restrict__ offs,
    const float* __restrict__ pos,
    int n, int maxn,
    int* __restrict__ to_idx,
    int* __restrict__ out_max) {
    __shared__ int hits[MAXHIT];

    const int row  = blockIdx.x;
    const int lane = threadIdx.x;

    const float px = pos[row*3], py = pos[row*3+1], pz = pos[row*3+2];
    int cx = (int)(px * 8.0f); cx = cx > 7 ? 7 : cx;
    int cy = (int)(py * 8.0f); cy = cy > 7 ? 7 : cy;
    int cz = (int)(pz * 8.0f); cz = cz > 7 ? 7 : cz;

    const unsigned long long lanemask = (1ull << lane) - 1ull;
    int base = 0;   // uncapped running hit count (wave-uniform)

    for (int dz = -1; dz <= 1; ++dz) {
        int czz = cz + dz; if (czz < 0 || czz > 7) continue;
        for (int dy = -1; dy <= 1; ++dy) {
            int cyy = cy + dy; if (cyy < 0 || cyy > 7) continue;
            int x0 = cx - 1 < 0 ? 0 : cx - 1;
            int x1 = cx + 1 > 7 ? 7 : cx + 1;
            int c0 = (czz * 8 + cyy) * 8 + x0;
            int s = offs[c0];
            int e = offs[c0 + (x1 - x0) + 1];
            for (int k0 = s; k0 < e; k0 += 64) {
                int k = k0 + lane;
                int kk = k < e ? k : e - 1;            // clamp, pred guards
                float4 q = sorted[kk];
                float dx = q.x - px, dyy = q.y - py, dzz = q.z - pz;
                float d2 = dx*dx + dyy*dyy + dzz*dzz;
                int idx = __float_as_int(q.w);
                bool pred = (k < e) && (d2 <= CUTOFF2) && (idx != row);
                unsigned long long m = __ballot(pred);
                int p = base + __popcll(m & lanemask);
                if (pred && p < MAXHIT) hits[p] = idx;
                base += (int)__popcll(m);
            }
        }
    }

    // pad unsorted tail with +inf sentinel, then bitonic-sort 128 slots
    int bmin = base < MAXHIT ? base : MAXHIT;
    for (int p = lane; p < MAXHIT; p += 64)
        if (p >= bmin) hits[p] = 0x7fffffff;
    __syncthreads();

    for (int k = 2; k <= MAXHIT; k <<= 1) {
        for (int j = k >> 1; j > 0; j >>= 1) {
            int i  = ((lane & ~(j - 1)) << 1) | (lane & (j - 1));
            int ix = i | j;
            int a = hits[i], b = hits[ix];
            bool up = ((i & k) == 0);
            int lo = a < b ? a : b;
            int hi = a < b ? b : a;
            hits[i]  = up ? lo : hi;
            hits[ix] = up ? hi : lo;
            __syncthreads();
        }
    }

    int* out_row = to_idx + (size_t)row * maxn;
    for (int p = lane; p < maxn; p += 64) {
        int v = (p < MAXHIT) ? hits[p] : 0x7fffffff;
        out_row[p] = (p < base) ? v : -1;
    }
    if (lane == 0) atomicMax(out_max, base);
}

extern "C" void kernel_launch(void* const* d_in, const int* in_sizes, int n_in,
                              void* d_out, int out_size, void* d_ws, size_t ws_size,
                              hipStream_t stream) {
    const float* pos = (const float*)d_in[0];
    const int n = in_sizes[0] / 3;                       // 8192
    const int maxn = (out_size - 1) / (n * 4);           // 128

    int* to_idx  = (int*)d_out;
    int* cells   = to_idx + (size_t)n * maxn;            // [n, maxn, 3]
    int* out_max = cells + (size_t)n * maxn * 3;         // scalar

    // workspace layout
    int*    cnt    = (int*)d_ws;                         // [512]
    int*    cursor = cnt + NCELLS;                       // [512]
    int*    offs   = cursor + NCELLS;                    // [513]
    float4* sorted = (float4*)((char*)d_ws + 8192);      // [n] 16B-aligned

    // zero cell counters/cursors; zero cell_indices + scalar output
    hipMemsetAsync(d_ws, 0, 2 * NCELLS * sizeof(int), stream);
    hipMemsetAsync(cells, 0, ((size_t)n * maxn * 3 + 1) * sizeof(int), stream);

    count_kernel  <<<(n + 255) / 256, 256, 0, stream>>>(pos, n, cnt);
    scan_kernel   <<<1, NCELLS, 0, stream>>>(cnt, offs);
    scatter_kernel<<<(n + 255) / 256, 256, 0, stream>>>(pos, n, offs, cursor, sorted);
    neigh_kernel  <<<n, 64, 0, stream>>>(sorted, offs, pos, n, maxn, to_idx, out_max);
}

// Round 3
// 88.977 us; speedup vs baseline: 2.0734x; 1.9639x over previous
//
#include <hip/hip_runtime.h>
#include <stdint.h>

// OpenBoundary neighbour list, N=8192, cutoff 0.125, max_neighbours=128.
// R3: bitmap-compaction design (no sort, no ballots, no block barriers in the
// hot kernel, no global atomics).
//   K1 bincount_scan : 1 block/512 thr — per-cell count (LDS atomics) +
//                      exclusive scan -> offs[513]; zeroes cursor[512].
//   K2 scatter       : cell-sorted float4 array, original idx in .w.
//   K3 neigh         : 2048 blocks x 256 thr, one wave64 per row. Stencil
//                      candidates gathered coalesced; hits set bits in a
//                      per-wave 1KB LDS bitmap (atomicOr, fully parallel).
//                      Lane-major bit enumeration + shfl prefix scan emits
//                      indices in globally ascending order (argwhere order).
//                      Uncapped count -> row_cnt[row] (plain store).
//   K4 maxred        : 1 block, max over row_cnt -> scalar output.
// cell_indices [N,128,3] zeroed by one 12MB memset.

#define CUTOFF2 (0.125f * 0.125f)
constexpr int NCELLS = 512;   // 8^3
constexpr int MAXN   = 128;

__device__ __forceinline__ int cell_of(float x, float y, float z) {
    int cx = (int)(x * 8.0f); cx = cx > 7 ? 7 : cx;
    int cy = (int)(y * 8.0f); cy = cy > 7 ? 7 : cy;
    int cz = (int)(z * 8.0f); cz = cz > 7 ? 7 : cz;
    return (cz * 8 + cy) * 8 + cx;
}

__global__ __launch_bounds__(512) void bincount_scan_kernel(
    const float* __restrict__ pos, int n,
    int* __restrict__ offs, int* __restrict__ cursor) {
    __shared__ int s[NCELLS];
    const int t = threadIdx.x;
    s[t] = 0;
    __syncthreads();
    for (int i = t; i < n; i += 512)
        atomicAdd(&s[cell_of(pos[i*3], pos[i*3+1], pos[i*3+2])], 1);
    __syncthreads();
    // Hillis-Steele inclusive scan over 512 cells
    for (int d = 1; d < NCELLS; d <<= 1) {
        int v = (t >= d) ? s[t - d] : 0;
        __syncthreads();
        s[t] += v;
        __syncthreads();
    }
    offs[t + 1] = s[t];
    if (t == 0) offs[0] = 0;
    cursor[t] = 0;
}

__global__ void scatter_kernel(const float* __restrict__ pos, int n,
                               const int* __restrict__ offs,
                               int* __restrict__ cursor,
                               float4* __restrict__ sorted) {
    int i = blockIdx.x * blockDim.x + threadIdx.x;
    if (i >= n) return;
    float x = pos[i*3], y = pos[i*3+1], z = pos[i*3+2];
    int c = cell_of(x, y, z);
    int slot = offs[c] + atomicAdd(&cursor[c], 1);
    sorted[slot] = make_float4(x, y, z, __int_as_float(i));
}

__global__ __launch_bounds__(256) void neigh_kernel(
    const float4* __restrict__ sorted,
    const int* __restrict__ offs,
    const float* __restrict__ pos,
    int n,
    int* __restrict__ to_idx,
    int* __restrict__ row_cnt) {
    // one 1KB bitmap (n/8 bytes) per wave; 4 waves per block
    __shared__ uint32_t bm[4][256];

    const int lane = threadIdx.x & 63;
    const int wave = threadIdx.x >> 6;
    const int row  = blockIdx.x * 4 + wave;
    uint32_t* mybm = bm[wave];

    // zero bitmap: one ds_write_b128 per lane
    ((int4*)mybm)[lane] = make_int4(0, 0, 0, 0);

    const float px = pos[row*3], py = pos[row*3+1], pz = pos[row*3+2];
    int cx = (int)(px * 8.0f); cx = cx > 7 ? 7 : cx;
    int cy = (int)(py * 8.0f); cy = cy > 7 ? 7 : cy;
    int cz = (int)(pz * 8.0f); cz = cz > 7 ? 7 : cz;

    // 3x3x3 stencil as up-to-9 contiguous x-runs; iterations independent
    for (int dz = -1; dz <= 1; ++dz) {
        int czz = cz + dz; if (czz < 0 || czz > 7) continue;
        for (int dy = -1; dy <= 1; ++dy) {
            int cyy = cy + dy; if (cyy < 0 || cyy > 7) continue;
            int x0 = cx - 1 < 0 ? 0 : cx - 1;
            int x1 = cx + 1 > 7 ? 7 : cx + 1;
            int c0 = (czz * 8 + cyy) * 8 + x0;
            int s = offs[c0];
            int e = offs[c0 + (x1 - x0) + 1];
            for (int k0 = s; k0 < e; k0 += 64) {
                int k = k0 + lane;
                int kk = k < e ? k : e - 1;
                float4 q = sorted[kk];
                float dx = q.x - px, dyv = q.y - py, dzv = q.z - pz;
                float d2 = dx*dx + dyv*dyv + dzv*dzv;
                int idx = __float_as_int(q.w);
                if ((k < e) && (d2 <= CUTOFF2) && (idx != row))
                    atomicOr(&mybm[idx >> 5], 1u << (idx & 31));
            }
        }
    }

    // read back this lane's 128-bit slice (lane-major => ascending indices)
    int4 wv = ((int4*)mybm)[lane];
    uint32_t w0 = (uint32_t)wv.x, w1 = (uint32_t)wv.y,
             w2 = (uint32_t)wv.z, w3 = (uint32_t)wv.w;
    int tc = __popc(w0) + __popc(w1) + __popc(w2) + __popc(w3);

    // inclusive shfl scan over 64 lanes
    int inc = tc;
    #pragma unroll
    for (int d = 1; d < 64; d <<= 1) {
        int o = __shfl_up(inc, d);
        if (lane >= d) inc += o;
    }
    const int total = __shfl(inc, 63);   // uncapped neighbour count
    int p = inc - tc;                    // exclusive prefix = output position

    int* out_row = to_idx + (size_t)row * MAXN;
    const int bitbase = lane << 7;       // lane*128
    uint32_t ws[4] = {w0, w1, w2, w3};
    #pragma unroll
    for (int d = 0; d < 4; ++d) {
        uint32_t m = ws[d];
        while (m) {
            int b = __ffs(m) - 1;
            if (p < MAXN) out_row[p] = bitbase + (d << 5) + b;
            ++p;
            m &= m - 1;
        }
    }
    // pad [min(total,128), 128) with -1 (disjoint from hit slots)
    int start = total < MAXN ? total : MAXN;
    for (int q = start + lane; q < MAXN; q += 64) out_row[q] = -1;

    if (lane == 0) row_cnt[row] = total;
}

__global__ __launch_bounds__(256) void maxred_kernel(
    const int* __restrict__ row_cnt, int n, int* __restrict__ out_max) {
    __shared__ int sm[4];
    int m = 0;
    for (int i = threadIdx.x; i < n; i += 256) {
        int v = row_cnt[i];
        m = v > m ? v : m;
    }
    #pragma unroll
    for (int d = 32; d > 0; d >>= 1) {
        int o = __shfl_down(m, d);
        m = o > m ? o : m;
    }
    if ((threadIdx.x & 63) == 0) sm[threadIdx.x >> 6] = m;
    __syncthreads();
    if (threadIdx.x == 0) {
        int r = sm[0];
        r = sm[1] > r ? sm[1] : r;
        r = sm[2] > r ? sm[2] : r;
        r = sm[3] > r ? sm[3] : r;
        *out_max = r;
    }
}

extern "C" void kernel_launch(void* const* d_in, const int* in_sizes, int n_in,
                              void* d_out, int out_size, void* d_ws, size_t ws_size,
                              hipStream_t stream) {
    const float* pos = (const float*)d_in[0];
    const int n = in_sizes[0] / 3;                       // 8192
    const int maxn = (out_size - 1) / (n * 4);           // 128

    int* to_idx  = (int*)d_out;
    int* cells   = to_idx + (size_t)n * maxn;            // [n, maxn, 3]
    int* out_max = cells + (size_t)n * maxn * 3;         // scalar

    // workspace: sorted float4[n] | offs[513] | cursor[512] | row_cnt[n]
    float4* sorted  = (float4*)d_ws;
    int*    offs    = (int*)((char*)d_ws + (size_t)n * sizeof(float4));
    int*    cursor  = offs + (NCELLS + 1);
    int*    row_cnt = cursor + NCELLS;

    // zero cell_indices (+scalar slot; overwritten by maxred anyway)
    hipMemsetAsync(cells, 0, ((size_t)n * maxn * 3 + 1) * sizeof(int), stream);

    bincount_scan_kernel<<<1, 512, 0, stream>>>(pos, n, offs, cursor);
    scatter_kernel<<<(n + 255) / 256, 256, 0, stream>>>(pos, n, offs, cursor, sorted);
    neigh_kernel<<<n / 4, 256, 0, stream>>>(sorted, offs, pos, n, to_idx, row_cnt);
    maxred_kernel<<<1, 256, 0, stream>>>(row_cnt, n, out_max);
}

// Round 4
// 86.540 us; speedup vs baseline: 2.1318x; 1.0282x over previous
//
#include <hip/hip_runtime.h>
#include <stdint.h>

// OpenBoundary neighbour list, N=8192, cutoff 0.125, max_neighbours=128.
// R4: scan-free padded-cell pipeline, 4 dispatches:
//   memset  : zero cnt[512] + partial[256] (3 KB)
//   scatter : point i -> cells[cell][atomicAdd(cnt[cell])] (order-free;
//             bitmap enumeration restores index order later)
//   neigh   : 1 wave64/row. 27-cell stencil fully unrolled; per cell one
//             predicated (lane < cnt) 16B load; hits -> per-wave 1KB LDS
//             bitmap (atomicOr). Lane-major bit enumeration + shfl scan
//             emits ascending indices (jnp.argwhere order). Also zeroes the
//             row's cell_indices[128][3] slice and atomicMax's the uncapped
//             count into partial[block & 255].
//   maxred  : max over 256 partials -> scalar output.

#define CUTOFF2 (0.125f * 0.125f)
constexpr int NCELLS = 512;   // 8^3
constexpr int CAP    = 64;    // slots/cell; occupancy ~Poisson(16), max~32
constexpr int MAXN   = 128;
constexpr int NPART  = 256;

__device__ __forceinline__ int ccoord(float v) {
    int c = (int)(v * 8.0f);
    return c > 7 ? 7 : c;
}

__global__ __launch_bounds__(256) void scatter_kernel(
    const float* __restrict__ pos, int n,
    int* __restrict__ cnt, float4* __restrict__ cells) {
    int i = blockIdx.x * blockDim.x + threadIdx.x;
    if (i >= n) return;
    float x = pos[i*3], y = pos[i*3+1], z = pos[i*3+2];
    int c = (ccoord(z) * 8 + ccoord(y)) * 8 + ccoord(x);
    int slot = atomicAdd(&cnt[c], 1);
    cells[c * CAP + slot] = make_float4(x, y, z, __int_as_float(i));
}

__global__ __launch_bounds__(256) void neigh_kernel(
    const float4* __restrict__ cells,
    const int* __restrict__ cnt,
    const float* __restrict__ pos,
    int maxn,
    int* __restrict__ to_idx,
    int* __restrict__ cell_out,     // [n, maxn, 3] zeros
    int* __restrict__ partial) {
    __shared__ uint32_t bm[4][256];

    const int lane = threadIdx.x & 63;
    const int wave = threadIdx.x >> 6;
    const int row  = blockIdx.x * 4 + wave;
    uint32_t* mybm = bm[wave];

    ((int4*)mybm)[lane] = make_int4(0, 0, 0, 0);   // zero bitmap (b128/lane)

    const float px = pos[row*3], py = pos[row*3+1], pz = pos[row*3+2];
    const int cx = ccoord(px), cy = ccoord(py), cz = ccoord(pz);

    // zero this row's cell_indices slice (96 int4), overlaps with loads
    int4* co = (int4*)(cell_out + (size_t)row * maxn * 3);
    co[lane] = make_int4(0, 0, 0, 0);
    if (lane < 32) co[64 + lane] = make_int4(0, 0, 0, 0);

    // 3x3x3 stencil, compile-time unrolled; predicated loads guard both
    // grid-boundary cells and unused (poisoned) slots via lane < cnt.
    #pragma unroll
    for (int dz = -1; dz <= 1; ++dz) {
        const int czz = cz + dz;
        const bool zok = (unsigned)czz <= 7u;
        #pragma unroll
        for (int dy = -1; dy <= 1; ++dy) {
            const int cyy = cy + dy;
            const bool yok = zok && ((unsigned)cyy <= 7u);
            #pragma unroll
            for (int dxc = -1; dxc <= 1; ++dxc) {
                const int cxx = cx + dxc;
                if (!(yok && ((unsigned)cxx <= 7u))) continue;
                const int c = (czz * 8 + cyy) * 8 + cxx;
                const int m = cnt[c];
                if (lane < m) {
                    float4 q = cells[c * CAP + lane];
                    float ddx = q.x - px, ddy = q.y - py, ddz = q.z - pz;
                    float d2 = ddx*ddx + ddy*ddy + ddz*ddz;
                    int idx = __float_as_int(q.w);
                    if (d2 <= CUTOFF2 && idx != row)
                        atomicOr(&mybm[idx >> 5], 1u << (idx & 31));
                }
            }
        }
    }

    // lane-major 128-bit slice -> ascending global index order
    int4 wv = ((int4*)mybm)[lane];
    uint32_t w0 = (uint32_t)wv.x, w1 = (uint32_t)wv.y,
             w2 = (uint32_t)wv.z, w3 = (uint32_t)wv.w;
    int tc = __popc(w0) + __popc(w1) + __popc(w2) + __popc(w3);

    int inc = tc;
    #pragma unroll
    for (int d = 1; d < 64; d <<= 1) {
        int o = __shfl_up(inc, d);
        if (lane >= d) inc += o;
    }
    const int total = __shfl(inc, 63);   // uncapped neighbour count
    int p = inc - tc;                    // exclusive prefix

    int* out_row = to_idx + (size_t)row * maxn;
    const int bitbase = lane << 7;
    uint32_t wsv[4] = {w0, w1, w2, w3};
    #pragma unroll
    for (int d = 0; d < 4; ++d) {
        uint32_t mm = wsv[d];
        while (mm) {
            int b = __ffs(mm) - 1;
            if (p < MAXN) out_row[p] = bitbase + (d << 5) + b;
            ++p;
            mm &= mm - 1;
        }
    }
    int start = total < MAXN ? total : MAXN;
    for (int q = start + lane; q < MAXN; q += 64) out_row[q] = -1;

    if (lane == 0) atomicMax(&partial[blockIdx.x & (NPART - 1)], total);
}

__global__ __launch_bounds__(256) void maxred_kernel(
    const int* __restrict__ partial, int* __restrict__ out_max) {
    __shared__ int sm[4];
    int m = partial[threadIdx.x];
    #pragma unroll
    for (int d = 32; d > 0; d >>= 1) {
        int o = __shfl_down(m, d);
        m = o > m ? o : m;
    }
    if ((threadIdx.x & 63) == 0) sm[threadIdx.x >> 6] = m;
    __syncthreads();
    if (threadIdx.x == 0) {
        int r = sm[0];
        r = sm[1] > r ? sm[1] : r;
        r = sm[2] > r ? sm[2] : r;
        r = sm[3] > r ? sm[3] : r;
        *out_max = r;
    }
}

extern "C" void kernel_launch(void* const* d_in, const int* in_sizes, int n_in,
                              void* d_out, int out_size, void* d_ws, size_t ws_size,
                              hipStream_t stream) {
    const float* pos = (const float*)d_in[0];
    const int n = in_sizes[0] / 3;                       // 8192
    const int maxn = (out_size - 1) / (n * 4);           // 128

    int* to_idx   = (int*)d_out;
    int* cell_out = to_idx + (size_t)n * maxn;           // [n, maxn, 3]
    int* out_max  = cell_out + (size_t)n * maxn * 3;     // scalar

    // ws: cnt[512] | partial[256] | pad | cells float4[512*64]
    int*    cnt     = (int*)d_ws;
    int*    partial = cnt + NCELLS;
    float4* cells   = (float4*)((char*)d_ws + 4096);

    hipMemsetAsync(d_ws, 0, (NCELLS + NPART) * sizeof(int), stream);
    scatter_kernel<<<(n + 255) / 256, 256, 0, stream>>>(pos, n, cnt, cells);
    neigh_kernel<<<n / 4, 256, 0, stream>>>(cells, cnt, pos, maxn,
                                            to_idx, cell_out, partial);
    maxred_kernel<<<1, NPART, 0, stream>>>(partial, out_max);
}